// Round 3
// baseline (194.865 us; speedup 1.0000x reference)
//
#include <hip/hip_runtime.h>

// PointPillarScatter: KITTI grid 432x496, 64 channels, B derived from out_size
#define PNX 432
#define PNY 496
#define PC  64

typedef float f32x4 __attribute__((ext_vector_type(4)));

// One thread per pillar: map[b*NY*NX + z + y*NX + x] = p (cells unique).
// Block 0 also zeroes the 64-float zero-row used by the gather's row fallback.
__global__ __launch_bounds__(256) void pps_scatter_idx(const int* __restrict__ coords,
                                                       int* __restrict__ map,
                                                       float* __restrict__ zrow, int P) {
    int p = blockIdx.x * blockDim.x + threadIdx.x;
    if (blockIdx.x == 0 && threadIdx.x < PC) zrow[threadIdx.x] = 0.f;
    if (p >= P) return;
    int b = coords[p * 4 + 0];
    int z = coords[p * 4 + 1];
    int y = coords[p * 4 + 2];
    int x = coords[p * 4 + 3];
    map[(size_t)b * (PNY * PNX) + z + y * PNX + x] = p;
}

// One thread per 8 consecutive cells (NY*NX % 8 == 0 -> never crosses batch).
// Loads are exec-mask skipped for lanes whose 8 cells are all empty (~44%+ of
// lanes skip); stores are CONVERGENT so every wave store is a dense 2KB burst.
__global__ __launch_bounds__(256) void pps_gather(const float* __restrict__ feat,
                                                  const int* __restrict__ map,
                                                  const float* __restrict__ zrow,
                                                  float* __restrict__ out, int ncell8) {
    int t = blockIdx.x * blockDim.x + threadIdx.x;
    if (t >= ncell8) return;
    int cell0 = t << 3;
    int b   = cell0 / (PNY * PNX);
    int loc = cell0 - b * (PNY * PNX);
    const size_t plane = (size_t)PNY * PNX;
    float* obase = out + (size_t)b * PC * plane + loc;

    int4 m0 = *reinterpret_cast<const int4*>(map + cell0);
    int4 m1 = *reinterpret_cast<const int4*>(map + cell0 + 4);
    int pid[8] = {m0.x, m0.y, m0.z, m0.w, m1.x, m1.y, m1.z, m1.w};
    // empties are exactly -1, so AND has sign bit set iff ALL 8 are empty
    int allAnd = pid[0] & pid[1] & pid[2] & pid[3] & pid[4] & pid[5] & pid[6] & pid[7];
    bool anyOcc = allAnd >= 0;

    const float* r[8];
#pragma unroll
    for (int i = 0; i < 8; ++i) r[i] = (pid[i] >= 0) ? feat + (size_t)pid[i] * PC : zrow;

#pragma unroll
    for (int cc = 0; cc < PC; cc += 8) {
        f32x4 v[8][2];
#pragma unroll
        for (int i = 0; i < 8; ++i) {
            v[i][0] = f32x4{0.f, 0.f, 0.f, 0.f};
            v[i][1] = f32x4{0.f, 0.f, 0.f, 0.f};
        }
        if (anyOcc) {   // exec-masked: all-empty lanes issue no loads
#pragma unroll
            for (int i = 0; i < 8; ++i) {
                v[i][0] = *reinterpret_cast<const f32x4*>(r[i] + cc);
                v[i][1] = *reinterpret_cast<const f32x4*>(r[i] + cc + 4);
            }
        }
        // convergent transposed stores: 2 dense float4 per plane per thread
#pragma unroll
        for (int j = 0; j < 8; ++j) {
            f32x4 lo = { v[0][j >> 2][j & 3], v[1][j >> 2][j & 3],
                         v[2][j >> 2][j & 3], v[3][j >> 2][j & 3] };
            f32x4 hi = { v[4][j >> 2][j & 3], v[5][j >> 2][j & 3],
                         v[6][j >> 2][j & 3], v[7][j >> 2][j & 3] };
            float* po = obase + (size_t)(cc + j) * plane;
            __builtin_nontemporal_store(lo, reinterpret_cast<f32x4*>(po));
            __builtin_nontemporal_store(hi, reinterpret_cast<f32x4*>(po + 4));
        }
    }
}

// ---------- fallback path (ws too small): zero + direct scatter ----------

__global__ __launch_bounds__(256) void pps_zero(float4* __restrict__ out4, int n4) {
    int i = blockIdx.x * blockDim.x + threadIdx.x;
    if (i < n4) out4[i] = make_float4(0.f, 0.f, 0.f, 0.f);
}

__global__ __launch_bounds__(256) void pps_scatter_feat(const float* __restrict__ feat,
                                                        const int* __restrict__ coords,
                                                        float* __restrict__ out, int total) {
    int g = blockIdx.x * blockDim.x + threadIdx.x;
    if (g >= total) return;
    int p = g >> 6;      // pillar
    int c = g & 63;      // channel
    int b = coords[p * 4 + 0];
    int z = coords[p * 4 + 1];
    int y = coords[p * 4 + 2];
    int x = coords[p * 4 + 3];
    const size_t plane = (size_t)PNY * PNX;
    out[((size_t)b * PC + c) * plane + z + y * PNX + x] = feat[g];
}

extern "C" void kernel_launch(void* const* d_in, const int* in_sizes, int n_in,
                              void* d_out, int out_size, void* d_ws, size_t ws_size,
                              hipStream_t stream) {
    const float* feat   = (const float*)d_in[0];
    const int*   coords = (const int*)d_in[1];
    float* out = (float*)d_out;

    const int P = in_sizes[1] / 4;                   // coords is [P,4]
    const int B = out_size / (PC * PNY * PNX);       // derive batch from out_size
    const size_t ncell = (size_t)B * PNY * PNX;      // divisible by 8
    const size_t mapbytes = ncell * sizeof(int);
    const size_t zoff = (mapbytes + 255) & ~(size_t)255;
    const size_t need = zoff + PC * sizeof(float);

    if (ws_size >= need) {
        int*   map  = (int*)d_ws;
        float* zrow = (float*)((char*)d_ws + zoff);
        // 0xFF bytes == int32 -1 : empty-cell marker
        hipMemsetAsync(map, 0xFF, mapbytes, stream);
        pps_scatter_idx<<<(P + 255) / 256, 256, 0, stream>>>(coords, map, zrow, P);
        int n8 = (int)(ncell / 8);
        pps_gather<<<(n8 + 255) / 256, 256, 0, stream>>>(feat, map, zrow, out, n8);
    } else {
        int n4 = out_size / 4;
        pps_zero<<<(n4 + 255) / 256, 256, 0, stream>>>((float4*)out, n4);
        int total = P * PC;
        pps_scatter_feat<<<(total + 255) / 256, 256, 0, stream>>>(feat, coords, out, total);
    }
}

// Round 4
// 102.046 us; speedup vs baseline: 1.9096x; 1.9096x over previous
//
#include <hip/hip_runtime.h>

// PointPillarScatter: KITTI grid 432x496, 64 channels, B derived from out_size
#define PNX 432
#define PNY 496
#define PC  64

typedef float f32x4 __attribute__((ext_vector_type(4)));

// One thread per pillar: map[b*NY*NX + z + y*NX + x] = p (cells unique).
// Block 0 also zeroes the 64-float zero-row used by the gather's row fallback.
__global__ __launch_bounds__(256) void pps_scatter_idx(const int* __restrict__ coords,
                                                       int* __restrict__ map,
                                                       float* __restrict__ zrow, int P) {
    int p = blockIdx.x * blockDim.x + threadIdx.x;
    if (blockIdx.x == 0 && threadIdx.x < PC) zrow[threadIdx.x] = 0.f;
    if (p >= P) return;
    int b = coords[p * 4 + 0];
    int z = coords[p * 4 + 1];
    int y = coords[p * 4 + 2];
    int x = coords[p * 4 + 3];
    map[(size_t)b * (PNY * PNX) + z + y * PNX + x] = p;
}

// Wave-adjacent x2 coarsened gather. Each lane owns two 4-cell groups:
//   g0 = wave*128 + lane, g1 = g0 + 64  (wave covers 512 consecutive cells)
// For each channel the wave issues two BACK-TO-BACK dense store instructions
// covering a contiguous 2KB span per plane. Every nt store instruction is
// fully dense at wave level (R3 lesson: nt + partial-density = 2x DRAM cost).
__global__ __launch_bounds__(256) void pps_gather(const float* __restrict__ feat,
                                                  const int* __restrict__ map,
                                                  const float* __restrict__ zrow,
                                                  float* __restrict__ out, int ngroups) {
    int t = blockIdx.x * blockDim.x + threadIdx.x;
    int wave = t >> 6, lane = t & 63;
    int g0 = (wave << 7) + lane;
    int g1 = g0 + 64;
    bool va = g0 < ngroups;
    bool vb = g1 < ngroups;
    if (!va) return;
    const size_t plane = (size_t)PNY * PNX;

    int ca = g0 << 2;
    int cb = vb ? (g1 << 2) : ca;          // clamp inactive group to a valid cell
    int ba = ca / (PNY * PNX), la = ca - ba * (PNY * PNX);
    int bb = cb / (PNY * PNX), lb = cb - bb * (PNY * PNX);

    int4 ma = *reinterpret_cast<const int4*>(map + ca);
    int4 mb = *reinterpret_cast<const int4*>(map + cb);
    int pa[4] = {ma.x, ma.y, ma.z, ma.w};
    int pb[4] = {mb.x, mb.y, mb.z, mb.w};
    const float* ra[4];
    const float* rb[4];
#pragma unroll
    for (int k = 0; k < 4; ++k) {
        ra[k] = (pa[k] >= 0) ? feat + (size_t)pa[k] * PC : zrow;
        rb[k] = (pb[k] >= 0) ? feat + (size_t)pb[k] * PC : zrow;
    }
    float* oa = out + (size_t)ba * PC * plane + la;
    float* ob = out + (size_t)bb * PC * plane + lb;

#pragma unroll
    for (int cc = 0; cc < PC; cc += 8) {
        f32x4 A[4][2], Bv[4][2];
#pragma unroll
        for (int k = 0; k < 4; ++k) {
            A[k][0]  = *reinterpret_cast<const f32x4*>(ra[k] + cc);
            A[k][1]  = *reinterpret_cast<const f32x4*>(ra[k] + cc + 4);
            Bv[k][0] = *reinterpret_cast<const f32x4*>(rb[k] + cc);
            Bv[k][1] = *reinterpret_cast<const f32x4*>(rb[k] + cc + 4);
        }
#pragma unroll
        for (int j = 0; j < 8; ++j) {
            f32x4 sa = { A[0][j >> 2][j & 3],  A[1][j >> 2][j & 3],
                         A[2][j >> 2][j & 3],  A[3][j >> 2][j & 3] };
            f32x4 sb = { Bv[0][j >> 2][j & 3], Bv[1][j >> 2][j & 3],
                         Bv[2][j >> 2][j & 3], Bv[3][j >> 2][j & 3] };
            size_t po = (size_t)(cc + j) * plane;
            __builtin_nontemporal_store(sa, reinterpret_cast<f32x4*>(oa + po));
            if (vb)
                __builtin_nontemporal_store(sb, reinterpret_cast<f32x4*>(ob + po));
        }
    }
}

// ---------- fallback path (ws too small): zero + direct scatter ----------

__global__ __launch_bounds__(256) void pps_zero(float4* __restrict__ out4, int n4) {
    int i = blockIdx.x * blockDim.x + threadIdx.x;
    if (i < n4) out4[i] = make_float4(0.f, 0.f, 0.f, 0.f);
}

__global__ __launch_bounds__(256) void pps_scatter_feat(const float* __restrict__ feat,
                                                        const int* __restrict__ coords,
                                                        float* __restrict__ out, int total) {
    int g = blockIdx.x * blockDim.x + threadIdx.x;
    if (g >= total) return;
    int p = g >> 6;      // pillar
    int c = g & 63;      // channel
    int b = coords[p * 4 + 0];
    int z = coords[p * 4 + 1];
    int y = coords[p * 4 + 2];
    int x = coords[p * 4 + 3];
    const size_t plane = (size_t)PNY * PNX;
    out[((size_t)b * PC + c) * plane + z + y * PNX + x] = feat[g];
}

extern "C" void kernel_launch(void* const* d_in, const int* in_sizes, int n_in,
                              void* d_out, int out_size, void* d_ws, size_t ws_size,
                              hipStream_t stream) {
    const float* feat   = (const float*)d_in[0];
    const int*   coords = (const int*)d_in[1];
    float* out = (float*)d_out;

    const int P = in_sizes[1] / 4;                   // coords is [P,4]
    const int B = out_size / (PC * PNY * PNX);       // derive batch from out_size
    const size_t ncell = (size_t)B * PNY * PNX;      // divisible by 4
    const size_t mapbytes = ncell * sizeof(int);
    const size_t zoff = (mapbytes + 255) & ~(size_t)255;
    const size_t need = zoff + PC * sizeof(float);

    if (ws_size >= need) {
        int*   map  = (int*)d_ws;
        float* zrow = (float*)((char*)d_ws + zoff);
        // 0xFF bytes == int32 -1 : empty-cell marker
        hipMemsetAsync(map, 0xFF, mapbytes, stream);
        pps_scatter_idx<<<(P + 255) / 256, 256, 0, stream>>>(coords, map, zrow, P);
        int ngroups = (int)(ncell / 4);
        int nthreads = (ngroups + 1) / 2;            // 2 groups per thread
        pps_gather<<<(nthreads + 255) / 256, 256, 0, stream>>>(feat, map, zrow, out, ngroups);
    } else {
        int n4 = out_size / 4;
        pps_zero<<<(n4 + 255) / 256, 256, 0, stream>>>((float4*)out, n4);
        int total = P * PC;
        pps_scatter_feat<<<(total + 255) / 256, 256, 0, stream>>>(feat, coords, out, total);
    }
}